// Round 1
// 699.325 us; speedup vs baseline: 1.0199x; 1.0199x over previous
//
#include <hip/hip_runtime.h>

// InstanceNorm over irreps 128x0e + 64x1e + 32x2e, fp32, segment-mean stats.
// batch sorted -> block-per-graph, contiguous row range.
// dim = 480 cols = 120 float4. Block = 1024 threads = 8 row-lanes x 128
// colgroups (120 active). 2 blocks/CU x 16 waves = 32 waves/CU (HW cap) --
// previous 512-thread version sat at 16 waves/CU and only reached 2.8 TB/s
// (latency-bound, VALUBusy 5.8%). __launch_bounds__(1024,8) pins VGPR<=64 so
// the 32-wave occupancy is actually achievable.

#define N_GRAPHS 512
#define DIM      480
#define VEC      120          // DIM / 4
#define RLANES   8            // row-lanes per block
#define EPSV     1e-5f

__device__ __forceinline__ int lower_bound_i32(const int* __restrict__ a, int n, int v) {
    int lo = 0, hi = n;
    while (lo < hi) {
        int mid = (lo + hi) >> 1;
        if (a[mid] < v) lo = mid + 1; else hi = mid;
    }
    return lo;
}

__device__ __forceinline__ float4 f4_add(float4 a, float4 b) {
    return make_float4(a.x + b.x, a.y + b.y, a.z + b.z, a.w + b.w);
}
__device__ __forceinline__ float4 f4_fma_sq(float4 a, float4 acc) {
    return make_float4(fmaf(a.x, a.x, acc.x), fmaf(a.y, a.y, acc.y),
                       fmaf(a.z, a.z, acc.z), fmaf(a.w, a.w, acc.w));
}

__global__ __launch_bounds__(1024, 8)
void instnorm_kernel(const float* __restrict__ in,
                     const float* __restrict__ weight,
                     const float* __restrict__ bias,
                     const int*   __restrict__ batch,
                     float*       __restrict__ out,
                     int n_nodes) {
    const int g  = blockIdx.x;
    const int t  = threadIdx.x;
    const int rl = t >> 7;        // row-lane 0..7
    const int cg = t & 127;       // colgroup 0..127 (active < 120)
    const bool active = (cg < VEC);

    __shared__ int   s_range[2];
    __shared__ float s_psum[RLANES * DIM];   // partial sums, [rl][col]
    __shared__ float s_psq [RLANES * DIM];
    __shared__ float s_sum[DIM];
    __shared__ float s_sq [DIM];
    __shared__ float s_sub[DIM];
    __shared__ float s_scale[DIM];
    __shared__ float s_add[DIM];

    // two independent binary searches in parallel (was serial on t==0)
    if (t < 2) s_range[t] = lower_bound_i32(batch, n_nodes, g + t);
    __syncthreads();
    const int start = s_range[0], end = s_range[1];

    const float4* __restrict__ in4  = (const float4*)in;
    float4*       __restrict__ out4 = (float4*)out;

    // ---- Pass 1: per-column sum / sumsq, 8 row-lanes in parallel ----
    float4 sum = make_float4(0.f, 0.f, 0.f, 0.f);
    float4 sq  = make_float4(0.f, 0.f, 0.f, 0.f);
    if (active) {
        int r = start + rl;
        for (; r + 24 < end; r += 32) {
            float4 x0 = in4[(size_t)(r +  0) * VEC + cg];
            float4 x1 = in4[(size_t)(r +  8) * VEC + cg];
            float4 x2 = in4[(size_t)(r + 16) * VEC + cg];
            float4 x3 = in4[(size_t)(r + 24) * VEC + cg];
            sum = f4_add(sum, f4_add(f4_add(x0, x1), f4_add(x2, x3)));
            sq  = f4_fma_sq(x0, sq); sq = f4_fma_sq(x1, sq);
            sq  = f4_fma_sq(x2, sq); sq = f4_fma_sq(x3, sq);
        }
        for (; r < end; r += RLANES) {
            float4 x = in4[(size_t)r * VEC + cg];
            sum = f4_add(sum, x);
            sq  = f4_fma_sq(x, sq);
        }
        ((float4*)s_psum)[rl * VEC + cg] = sum;
        ((float4*)s_psq )[rl * VEC + cg] = sq;
    }
    __syncthreads();

    // combine the 8 row-lane partials -> s_sum/s_sq (float4 granularity)
    if (t < VEC) {
        float4 a = ((float4*)s_psum)[t];
        float4 b = ((float4*)s_psq)[t];
        #pragma unroll
        for (int l = 1; l < RLANES; ++l) {
            a = f4_add(a, ((float4*)s_psum)[l * VEC + t]);
            b = f4_add(b, ((float4*)s_psq )[l * VEC + t]);
        }
        ((float4*)s_sum)[t] = a;
        ((float4*)s_sq )[t] = b;
    }
    __syncthreads();

    // ---- Per-column normalization parameters (c = t < 480) ----
    const float cntf = (float)max(end - start, 1);
    const int c = t;
    if (c < 128) {
        float mean = s_sum[c] / cntf;
        float var  = s_sq[c] / cntf - mean * mean;
        var = fmaxf(var, 0.f);
        float sc = weight[c] / sqrtf(var + EPSV);
        s_sub[c] = mean; s_scale[c] = sc; s_add[c] = bias[c];
    } else if (c < 320) {
        int k = (c - 128) / 3;
        int base = 128 + k * 3;
        float fn = (s_sq[base] + s_sq[base + 1] + s_sq[base + 2]) / (3.f * cntf);
        float sc = weight[128 + k] / sqrtf(fn + EPSV);
        s_sub[c] = 0.f; s_scale[c] = sc; s_add[c] = 0.f;
    } else if (c < DIM) {
        int k = (c - 320) / 5;
        int base = 320 + k * 5;
        float fn = (s_sq[base] + s_sq[base + 1] + s_sq[base + 2] +
                    s_sq[base + 3] + s_sq[base + 4]) / (5.f * cntf);
        float sc = weight[192 + k] / sqrtf(fn + EPSV);
        s_sub[c] = 0.f; s_scale[c] = sc; s_add[c] = 0.f;
    }
    __syncthreads();

    // ---- Pass 2: apply (x - sub) * scale + add, float4, unroll 4 ----
    if (active) {
        const float4 sub = ((const float4*)s_sub)[cg];
        const float4 scl = ((const float4*)s_scale)[cg];
        const float4 add = ((const float4*)s_add)[cg];
        int r = start + rl;
        for (; r + 24 < end; r += 32) {
            float4 x0 = in4[(size_t)(r +  0) * VEC + cg];
            float4 x1 = in4[(size_t)(r +  8) * VEC + cg];
            float4 x2 = in4[(size_t)(r + 16) * VEC + cg];
            float4 x3 = in4[(size_t)(r + 24) * VEC + cg];
            float4 y0 = make_float4(fmaf(x0.x - sub.x, scl.x, add.x),
                                    fmaf(x0.y - sub.y, scl.y, add.y),
                                    fmaf(x0.z - sub.z, scl.z, add.z),
                                    fmaf(x0.w - sub.w, scl.w, add.w));
            float4 y1 = make_float4(fmaf(x1.x - sub.x, scl.x, add.x),
                                    fmaf(x1.y - sub.y, scl.y, add.y),
                                    fmaf(x1.z - sub.z, scl.z, add.z),
                                    fmaf(x1.w - sub.w, scl.w, add.w));
            float4 y2 = make_float4(fmaf(x2.x - sub.x, scl.x, add.x),
                                    fmaf(x2.y - sub.y, scl.y, add.y),
                                    fmaf(x2.z - sub.z, scl.z, add.z),
                                    fmaf(x2.w - sub.w, scl.w, add.w));
            float4 y3 = make_float4(fmaf(x3.x - sub.x, scl.x, add.x),
                                    fmaf(x3.y - sub.y, scl.y, add.y),
                                    fmaf(x3.z - sub.z, scl.z, add.z),
                                    fmaf(x3.w - sub.w, scl.w, add.w));
            out4[(size_t)(r +  0) * VEC + cg] = y0;
            out4[(size_t)(r +  8) * VEC + cg] = y1;
            out4[(size_t)(r + 16) * VEC + cg] = y2;
            out4[(size_t)(r + 24) * VEC + cg] = y3;
        }
        for (; r < end; r += RLANES) {
            float4 x = in4[(size_t)r * VEC + cg];
            out4[(size_t)r * VEC + cg] =
                make_float4(fmaf(x.x - sub.x, scl.x, add.x),
                            fmaf(x.y - sub.y, scl.y, add.y),
                            fmaf(x.z - sub.z, scl.z, add.z),
                            fmaf(x.w - sub.w, scl.w, add.w));
        }
    }
}

extern "C" void kernel_launch(void* const* d_in, const int* in_sizes, int n_in,
                              void* d_out, int out_size, void* d_ws, size_t ws_size,
                              hipStream_t stream) {
    const float* in     = (const float*)d_in[0];
    const float* weight = (const float*)d_in[1];
    const float* bias   = (const float*)d_in[2];
    const int*   batch  = (const int*)d_in[3];
    float*       out    = (float*)d_out;
    const int n_nodes   = in_sizes[3];   // 200000

    instnorm_kernel<<<N_GRAPHS, 1024, 0, stream>>>(in, weight, bias, batch, out, n_nodes);
}